// Round 11
// baseline (329.860 us; speedup 1.0000x reference)
//
#include <hip/hip_runtime.h>
#include <hip/hip_bf16.h>
#include <cstdint>
#include <cstddef>

typedef __bf16 bf16_t;
typedef _Float16 f16_t;
typedef __bf16 bf16x4 __attribute__((ext_vector_type(4)));
typedef __bf16 bf16x8 __attribute__((ext_vector_type(8)));
typedef float  f32x16 __attribute__((ext_vector_type(16)));

constexpr int kBatch = 4;
constexpr int kT = 4096;
constexpr int kD = 1024;
constexpr int kM = kBatch * kT;     // 16384 rows
constexpr int kCH = kBatch * kD;    // 4096 scan channels
constexpr int kNC = 128;            // scan chunks
constexpr int kL  = kT / kNC;       // 32 steps per chunk
constexpr int LDS_BYTES = 131072;   // 4 bufs x 32KB (A 16K + B 16K each)

// ================================================================ TILED FORMAT v2
// [R][C] bf16 stored as (R/128)x(C/32) tiles of 128x32 = 4096 elem (8KB).
// tile = (r>>7)*(C/32) + (c>>5)
// off  = ((r>>5)&3)<<10 | ((c>>4)&1)<<9 | ((c>>3)&1)<<8 | ((r&31)<<3) | (c&7)
// Granule: 16B = (fixed r, 8 consecutive c) == the 32x32x16 MFMA lane fragment.
// GEMM staging is a pure linear 8KB copy; fragment read = contiguous 1024B
// block at base+lane*16 (R8/R10-verified: zero bank conflicts).
__device__ __forceinline__ size_t tidx(int r, int c, int ntc) {
    return (size_t)((r >> 7) * ntc + (c >> 5)) * 4096
         + (((r >> 5) & 3) << 10) + (((c >> 4) & 1) << 9)
         + (((c >> 3) & 1) << 8) + ((r & 31) << 3) + (c & 7);
}

// ---------------------------------------------------------------- helpers
__device__ __forceinline__ void async16(const bf16_t* g, char* l) {
    __builtin_amdgcn_global_load_lds(
        (const __attribute__((address_space(1))) uint32_t*)g,
        (__attribute__((address_space(3))) uint32_t*)l,
        16, 0, 0);
}

__device__ __forceinline__ float fast_sigmoid(float z) {
    return 1.f / (1.f + __expf(-z));
}
__device__ __forceinline__ float fast_tanh(float z) {
    z = fminf(10.f, fmaxf(-10.f, z));
    float e = __expf(2.f * z);
    return (e - 1.f) / (e + 1.f);
}

// ---------------------------------------------------------------- merged tiled cast
// One launch: x (4096 tiles) + 5 weights (256 tiles each). Direct tiled write
// (no LDS): per-thread bf16x4 stores; 16-thread groups cover 128B segments.
__global__ __launch_bounds__(256)
void cvt2_kernel(const float* __restrict__ x,
                 const float* __restrict__ w0, const float* __restrict__ w1,
                 const float* __restrict__ w2, const float* __restrict__ w3,
                 const float* __restrict__ w4,
                 bf16_t* __restrict__ xd, bf16_t* __restrict__ wd)
{
    int tile = blockIdx.x;
    const float* src; bf16_t* dst; int loc;
    if (tile < 4096) { src = x; dst = xd; loc = tile; }
    else {
        int seg = (tile - 4096) >> 8;
        loc = (tile - 4096) & 255;
        src = seg == 0 ? w0 : seg == 1 ? w1 : seg == 2 ? w2 : seg == 3 ? w3 : w4;
        dst = wd + (size_t)seg * kD * kD;
    }
    const int rt = loc >> 5, ct = loc & 31;      // ntc = 32 (K = 1024 cols)
    const int t = threadIdx.x;
    const int c4 = t & 7;                        // float4 col within tile
    const int r0 = t >> 3;                       // row 0..31
    bf16_t* db = dst + (size_t)loc * 4096
               + (((c4 >> 2) & 1) << 9) + (((c4 >> 1) & 1) << 8)
               + (r0 << 3) + ((c4 & 1) << 2);
#pragma unroll
    for (int j = 0; j < 4; ++j) {
        const int r = r0 + j * 32;
        float4 a = reinterpret_cast<const float4*>(src)[(size_t)(rt * 128 + r) * 256 + ct * 8 + c4];
        bf16x4 o;
        o[0] = (bf16_t)a.x; o[1] = (bf16_t)a.y; o[2] = (bf16_t)a.z; o[3] = (bf16_t)a.w;
        *reinterpret_cast<bf16x4*>(db + (j << 10)) = o;
    }
}

// ---------------------------------------------------------------- 256x256 BK=32 GEMM
// Depth-3 software pipeline: 4 LDS buffers; prologue stages tiles 0..2; per
// iter w: {counted vmcnt(8) [tiles w+1,w+2 stay in flight]; barrier; 12
// ds_reads; stage tile w+3 -> buf[(w+3)&3] (its readers finished before this
// barrier); 16 MFMA (setprio)}. Tail: vmcnt(4)/vmcnt(0). Loads get ~3 K-tiles
// of latency cover; the queue is never drained mid-loop (T4).
// Operands in TILED v2 format: staging = linear 8KB copies; fragment reads =
// contiguous 1024B (0 conflicts). 8 waves (2M x 4N), per-wave 128x64 out.
// C/D layout (m74/m101): col=lane&31, row=(reg&3)+8*(reg>>2)+4*(lane>>5).
// EPI: 0 silu->bf16 TILED | 3 f32 nt row-major | 4 slab0 sigmoid->f16 /
//      slab1 sigmoid->bf16 / slab2 tanh->bf16 (row-major)
template<int EPI>
__global__ __launch_bounds__(512, 2)
void gemm256(const bf16_t* __restrict__ A, const bf16_t* __restrict__ Bw,
             const float* __restrict__ bi0, const float* __restrict__ bi1,
             const float* __restrict__ bi2,
             void* __restrict__ out0, void* __restrict__ out1, void* __restrict__ out2,
             int M, int N, int K)
{
    extern __shared__ char lds[];
    const int tid  = threadIdx.x;
    const int lane = tid & 63;
    const int wv   = tid >> 6;
    const int wr   = wv >> 2;      // 0..1  (M waves, 128 rows each)
    const int wc   = wv & 3;       // 0..3  (N waves, 64 cols each)
    const int l32  = lane & 31;
    const int lh   = lane >> 5;    // k-half selector

    // ---- bijective XCD-chunk swizzle (nwg % 8 == 0 for all our grids) ----
    int bid = blockIdx.y * gridDim.x + blockIdx.x;
    int nwg = gridDim.x * gridDim.y;
    int swz = (bid & 7) * (nwg >> 3) + (bid >> 3);
    int gx  = N >> 8;
    int n0  = (swz % gx) << 8;
    int m0  = (swz / gx) << 8;

    const int ntcK = K >> 5;               // col-tiles (32)
    const size_t rstride = (size_t)ntcK * 4096;
    const size_t atile0 = (size_t)(m0 >> 7) * rstride;
    const size_t atile1 = atile0 + rstride;
    const size_t btile0 = (size_t)(n0 >> 7) * rstride;
    const size_t btile1 = btile0 + rstride;
    const size_t g = (size_t)tid * 8;      // linear element offset in a tile
    const int tid16 = tid << 4;

    auto STAGE_TILE = [&](int w, int bufo) {
        const size_t kt = (size_t)w * 4096;
        async16(A  + atile0 + kt + g, lds + bufo + tid16);
        async16(A  + atile1 + kt + g, lds + bufo + 8192  + tid16);
        async16(Bw + btile0 + kt + g, lds + bufo + 16384 + tid16);
        async16(Bw + btile1 + kt + g, lds + bufo + 24576 + tid16);
    };

    // ---- fragment read offsets (within an 8KB region): contiguous 1KB blocks ----
    const int lane16 = lane << 4;
    const int aRegO = wr << 13;                         // A half region
    const int bRegO = 16384 + ((wc >> 1) << 13);        // B half region
    int offA[2][4], offB[2][2];
#pragma unroll
    for (int ks = 0; ks < 2; ++ks) {
#pragma unroll
        for (int m = 0; m < 4; ++m)
            offA[ks][m] = aRegO + (m << 11) + (ks << 10) + lane16;
#pragma unroll
        for (int n = 0; n < 2; ++n)
            offB[ks][n] = bRegO + ((((wc & 1) << 1) + n) << 11) + (ks << 10) + lane16;
    }

    f32x16 acc[4][2];
#pragma unroll
    for (int i = 0; i < 4; ++i)
#pragma unroll
        for (int j = 0; j < 2; ++j)
            acc[i][j] = (f32x16)(0.f);

    const int NT = K >> 5;   // 32

    // ---- prologue: stage tiles 0..2 into bufs 0..2 ----
    STAGE_TILE(0, 0);
    STAGE_TILE(1, 32768);
    STAGE_TILE(2, 65536);

    for (int w = 0; w < NT; ++w) {
        const int bufo = (w & 3) << 15;
        if (w + 2 < NT)      { asm volatile("s_waitcnt vmcnt(8)" ::: "memory"); }
        else if (w + 1 < NT) { asm volatile("s_waitcnt vmcnt(4)" ::: "memory"); }
        else                 { asm volatile("s_waitcnt vmcnt(0)" ::: "memory"); }
        asm volatile("s_barrier" ::: "memory");

        bf16x8 aF[2][4], bF[2][2];
#pragma unroll
        for (int ks = 0; ks < 2; ++ks) {
#pragma unroll
            for (int m = 0; m < 4; ++m)
                aF[ks][m] = *reinterpret_cast<const bf16x8*>(lds + bufo + offA[ks][m]);
#pragma unroll
            for (int n = 0; n < 2; ++n)
                bF[ks][n] = *reinterpret_cast<const bf16x8*>(lds + bufo + offB[ks][n]);
        }
        // stage tile w+3 into buf[(w+3)&3] == buf[(w-1)&3]; its readers ran in
        // iter w-1, before the barrier above -> safe.
        if (w + 3 < NT) STAGE_TILE(w + 3, ((w + 3) & 3) << 15);

        __builtin_amdgcn_s_setprio(1);
#pragma unroll
        for (int ks = 0; ks < 2; ++ks)
#pragma unroll
            for (int m = 0; m < 4; ++m)
#pragma unroll
                for (int n = 0; n < 2; ++n)
                    acc[m][n] = __builtin_amdgcn_mfma_f32_32x32x16_bf16(aF[ks][m], bF[ks][n], acc[m][n], 0, 0, 0);
        __builtin_amdgcn_s_setprio(0);
    }

    // ---- epilogue: 32x32 C/D layout col=lane&31, row=(reg&3)+8*(reg>>2)+4*lh ----
    const int slab = n0 >> 10;                 // block-uniform (EPI==4)
    const float* bia = (EPI == 4) ? (slab == 0 ? bi0 : slab == 1 ? bi1 : bi2) : nullptr;
#pragma unroll
    for (int nf = 0; nf < 2; ++nf) {
        const int colg = n0 + wc * 64 + nf * 32 + l32;
        const int cL = colg & (kD - 1);
        float bs = 0.f;
        if constexpr (EPI == 4) bs = bia[cL];
#pragma unroll
        for (int mf = 0; mf < 4; ++mf) {
            const int rbase = m0 + wr * 128 + mf * 32 + lh * 4;
#pragma unroll
            for (int rg = 0; rg < 16; ++rg) {
                const int rowg = rbase + (rg & 3) + ((rg >> 2) << 3);
                const float f = acc[mf][nf][rg];
                if constexpr (EPI == 0) {
                    float s = f * fast_sigmoid(f);
                    reinterpret_cast<bf16_t*>(out0)[tidx(rowg, colg, N >> 5)] = (bf16_t)s;
                } else if constexpr (EPI == 3) {
                    __builtin_nontemporal_store(f, reinterpret_cast<float*>(out0) + (size_t)rowg * N + colg);
                } else {  // EPI == 4
                    const size_t idx = (size_t)rowg * kD + cL;
                    if (slab == 0) {
                        reinterpret_cast<f16_t*>(out0)[idx] = (f16_t)fast_sigmoid(f + bs);
                    } else if (slab == 1) {
                        reinterpret_cast<bf16_t*>(out1)[idx] = (bf16_t)fast_sigmoid(f + bs);
                    } else {
                        reinterpret_cast<bf16_t*>(out2)[idx] = (bf16_t)fast_tanh(f + bs);
                    }
                }
            }
        }
    }
}

// ---------------------------------------------------------------- chunked linear scan
// h_t = a_t*h + beta_t*v_t ; alpha fp16, beta/v bf16 (row-major).
__global__ void scan_chunk_kernel(const f16_t* __restrict__ alpha,
                                  const bf16_t* __restrict__ beta,
                                  const bf16_t* __restrict__ vv,
                                  float* __restrict__ Aagg,
                                  float* __restrict__ Bagg)
{
    const int u  = blockIdx.x * blockDim.x + threadIdx.x;
    const int ch = u & (kCH - 1);
    const int c  = u >> 12;
    const int b  = ch >> 10;
    const int d  = ch & (kD - 1);
    size_t base = ((size_t)b * kT + (size_t)c * kL) * kD + d;
    float Ac = 1.f, Bc = 0.f;
#pragma unroll 4
    for (int t = 0; t < kL; ++t) {
        float a  = (float)alpha[base];
        float bv = (float)beta[base] * (float)vv[base];
        Ac *= a;
        Bc = a * Bc + bv;
        base += kD;
    }
    Aagg[u] = Ac;
    Bagg[u] = Bc;
}

__global__ void scan_mid_kernel(const float* __restrict__ Aagg,
                                const float* __restrict__ Bagg,
                                float* __restrict__ Hin,
                                float* __restrict__ hlast)
{
    const int ch = blockIdx.x * blockDim.x + threadIdx.x;
    float h = 0.f;
#pragma unroll 8
    for (int c = 0; c < kNC; ++c) {
        Hin[(size_t)c * kCH + ch] = h;
        h = Aagg[(size_t)c * kCH + ch] * h + Bagg[(size_t)c * kCH + ch];
    }
    hlast[ch] = h;
}

// writes cell in TILED v2 format; each thread's 32 t-steps cover one
// contiguous 512B span (stride +16B per t).
__global__ void scan_out_kernel(const f16_t* __restrict__ alpha,
                                const bf16_t* __restrict__ beta,
                                const bf16_t* __restrict__ vv,
                                const float* __restrict__ Hin,
                                bf16_t* __restrict__ cell)
{
    const int u  = blockIdx.x * blockDim.x + threadIdx.x;
    const int ch = u & (kCH - 1);
    const int c  = u >> 12;
    const int b  = ch >> 10;
    const int d  = ch & (kD - 1);
    size_t base = ((size_t)b * kT + (size_t)c * kL) * kD + d;
    // tiled dest: r = b*kT + c*kL + t -> rt = b*32 + (c>>2), mb = c&3, r32 = t
    const size_t tb = (size_t)((b * 32 + (c >> 2)) * 32 + (d >> 5)) * 4096
                    + ((size_t)(c & 3) << 10) + (((d >> 4) & 1) << 9)
                    + (((d >> 3) & 1) << 8) + (d & 7);
    float h = Hin[u];
#pragma unroll 4
    for (int t = 0; t < kL; ++t) {
        float a  = (float)alpha[base];
        float bv = (float)beta[base] * (float)vv[base];
        h = a * h + bv;
        float s = 1.f / (1.f + __expf(-h));
        cell[tb + t * 8] = (bf16_t)(h * h * s);
        base += kD;
    }
}

// ---------------------------------------------------------------- launch
extern "C" void kernel_launch(void* const* d_in, const int* in_sizes, int n_in,
                              void* d_out, int out_size, void* d_ws, size_t ws_size,
                              hipStream_t stream)
{
    const float* x     = (const float*)d_in[0];
    const float* W_in  = (const float*)d_in[1];
    const float* W_al  = (const float*)d_in[2];
    const float* b_al  = (const float*)d_in[3];
    const float* W_be  = (const float*)d_in[4];
    const float* b_be  = (const float*)d_in[5];
    const float* W_v   = (const float*)d_in[6];
    const float* b_v   = (const float*)d_in[7];
    const float* W_out = (const float*)d_in[8];

    float* out   = (float*)d_out;
    float* hlast = out + (size_t)kM * kD;

    char* ws = (char*)d_ws;
    size_t off = 0;
    auto alloc = [&](size_t bytes) -> void* {
        void* p = ws + off;
        off += (bytes + 255) & ~(size_t)255;
        return p;
    };
    bf16_t* xbf   = (bf16_t*)alloc((size_t)kM * kD * 2);   // tiled; reused as cell
    bf16_t* xp    = (bf16_t*)alloc((size_t)kM * kD * 2);   // tiled; reused for aggs
    f16_t*  alpha = (f16_t*) alloc((size_t)kM * kD * 2);
    bf16_t* betab = (bf16_t*)alloc((size_t)kM * kD * 2);
    bf16_t* vb    = (bf16_t*)alloc((size_t)kM * kD * 2);
    bf16_t* wbf   = (bf16_t*)alloc((size_t)5 * kD * kD * 2);

    bf16_t* Winb = wbf;                         // tiled [W_in; W_al; W_be; W_v; W_out]
    bf16_t* Wfus = wbf + 1 * (size_t)kD * kD;   // fused B: row-tiles 0..23
    bf16_t* Wob  = wbf + 4 * (size_t)kD * kD;

    bf16_t* cell = xbf;
    float*  Aagg = (float*)xp;
    float*  Bagg = Aagg + (size_t)kNC * kCH;
    float*  Hin  = Bagg + (size_t)kNC * kCH;

    hipFuncSetAttribute(reinterpret_cast<const void*>(gemm256<0>), hipFuncAttributeMaxDynamicSharedMemorySize, LDS_BYTES);
    hipFuncSetAttribute(reinterpret_cast<const void*>(gemm256<3>), hipFuncAttributeMaxDynamicSharedMemorySize, LDS_BYTES);
    hipFuncSetAttribute(reinterpret_cast<const void*>(gemm256<4>), hipFuncAttributeMaxDynamicSharedMemorySize, LDS_BYTES);

    // 1) single merged tiled cast: x (4096 tiles) + 5 weights (5*256 tiles)
    cvt2_kernel<<<4096 + 5 * 256, 256, 0, stream>>>(x, W_in, W_al, W_be, W_v, W_out,
                                                    xbf, wbf);

    dim3 grid1(kD / 256, kM / 256);     // (4, 64)  = 256 wgs
    dim3 gridF(3 * kD / 256, kM / 256); // (12, 64) = 768 wgs

    // 2) xp = silu(x @ W_in^T)                       [bf16 tiled]
    gemm256<0><<<grid1, 512, LDS_BYTES, stream>>>(xbf, Winb, nullptr, nullptr, nullptr,
                                                  xp, nullptr, nullptr, kM, kD, kD);
    // 3) fused: alpha=sigmoid(+b_al) f16 | beta=sigmoid(+b_be) bf16 | v=tanh(+b_v) bf16
    gemm256<4><<<gridF, 512, LDS_BYTES, stream>>>(xp, Wfus, b_al, b_be, b_v,
                                                  alpha, betab, vb, kM, 3 * kD, kD);
    // 4) chunked scan (bv = beta*v on the fly); cell written tiled
    scan_chunk_kernel<<<kNC * kCH / 256, 256, 0, stream>>>(alpha, betab, vb, Aagg, Bagg);
    scan_mid_kernel<<<kCH / 256, 256, 0, stream>>>(Aagg, Bagg, Hin, hlast);
    scan_out_kernel<<<kNC * kCH / 256, 256, 0, stream>>>(alpha, betab, vb, Hin, cell);

    // 5) output = cell @ W_out^T                     [f32 nt -> d_out]
    gemm256<3><<<grid1, 512, LDS_BYTES, stream>>>(cell, Wob, nullptr, nullptr, nullptr,
                                                  out, nullptr, nullptr, kM, kD, kD);
}

// Round 12
// 308.100 us; speedup vs baseline: 1.0706x; 1.0706x over previous
//
#include <hip/hip_runtime.h>
#include <hip/hip_bf16.h>
#include <cstdint>
#include <cstddef>

typedef __bf16 bf16_t;
typedef _Float16 f16_t;
typedef __bf16 bf16x2 __attribute__((ext_vector_type(2)));
typedef __bf16 bf16x4 __attribute__((ext_vector_type(4)));
typedef __bf16 bf16x8 __attribute__((ext_vector_type(8)));
typedef _Float16 f16x2 __attribute__((ext_vector_type(2)));
typedef float  f32x16 __attribute__((ext_vector_type(16)));

constexpr int kBatch = 4;
constexpr int kT = 4096;
constexpr int kD = 1024;
constexpr int kM = kBatch * kT;     // 16384 rows
constexpr int kCH = kBatch * kD;    // 4096 scan channels
constexpr int kNC = 128;            // scan chunks
constexpr int kL  = kT / kNC;       // 32 steps per chunk
constexpr int LDS_BYTES = 131072;   // 2 bufs x (A 32K + B 32K)

// ================================================================ TILED FORMAT (v1)
// [R][1024] bf16 stored as (R/128)x16 tiles of 128x64, each tile 16KB:
//   tile = (r>>7)*16 + (c>>6)
//   off  = ((r>>5)&3)*2048 + ((c>>4)&3)*512 + ((c>>3)&1)*256 + (r&31)*8 + (c&7)
// GEMM staging = pure linear 16KB copy; each 32x32x16 MFMA fragment read is
// one contiguous 1024B block (R8/R10-measured: zero bank conflicts).
__device__ __forceinline__ size_t tiled_idx(int r, int c, int ktiles) {
    return (size_t)((r >> 7) * ktiles + (c >> 6)) * 8192
         + (((r >> 5) & 3) << 11) + (((c >> 4) & 3) << 9)
         + (((c >> 3) & 1) << 8) + ((r & 31) << 3) + (c & 7);
}

// ---------------------------------------------------------------- helpers
__device__ __forceinline__ void async16(const bf16_t* g, char* l) {
    __builtin_amdgcn_global_load_lds(
        (const __attribute__((address_space(1))) uint32_t*)g,
        (__attribute__((address_space(3))) uint32_t*)l,
        16, 0, 0);
}

__device__ __forceinline__ float fast_sigmoid(float z) {
    return 1.f / (1.f + __expf(-z));
}
__device__ __forceinline__ float fast_tanh(float z) {
    z = fminf(10.f, fmaxf(-10.f, z));
    float e = __expf(2.f * z);
    return (e - 1.f) / (e + 1.f);
}

// ---------------------------------------------------------------- merged tiled cast
// ONE launch: x (2048 tiles) + 5 weights (128 tiles each). Per-tile LDS
// transpose: coalesced float4 reads -> tiled order in LDS -> linear 16KB write.
__global__ __launch_bounds__(256)
void cvt_all_kernel(const float* __restrict__ x,
                    const float* __restrict__ w0, const float* __restrict__ w1,
                    const float* __restrict__ w2, const float* __restrict__ w3,
                    const float* __restrict__ w4,
                    bf16_t* __restrict__ xd, bf16_t* __restrict__ wd)
{
    __shared__ __align__(16) bf16_t sl[8192];
    int tile = blockIdx.x;
    const float* src; bf16_t* dst; int loc;
    if (tile < 2048) { src = x; dst = xd; loc = tile; }
    else {
        int seg = (tile - 2048) >> 7;
        loc = (tile - 2048) & 127;
        src = seg == 0 ? w0 : seg == 1 ? w1 : seg == 2 ? w2 : seg == 3 ? w3 : w4;
        dst = wd + (size_t)seg * kD * kD;
    }
    const int rt = loc >> 4, kt = loc & 15;
    const int tid = threadIdx.x;
    const int c4 = tid & 15;            // float4 col within tile (0..15)
    const int rl0 = tid >> 4;           // row stride 16
    const int coff = (((c4 >> 2) & 3) << 9) + (((c4 >> 1) & 1) << 8) + ((c4 & 1) << 2);
#pragma unroll
    for (int p = 0; p < 8; ++p) {
        const int r = p * 16 + rl0;
        float4 a = reinterpret_cast<const float4*>(src)[(size_t)(rt * 128 + r) * 256 + kt * 16 + c4];
        bf16x4 o;
        o[0] = (bf16_t)a.x; o[1] = (bf16_t)a.y; o[2] = (bf16_t)a.z; o[3] = (bf16_t)a.w;
        *reinterpret_cast<bf16x4*>(&sl[((r >> 5) << 11) + ((r & 31) << 3) + coff]) = o;
    }
    __syncthreads();
    bf16x8* d8 = reinterpret_cast<bf16x8*>(dst) + (size_t)loc * 1024;
    const bf16x8* s8 = reinterpret_cast<const bf16x8*>(sl);
#pragma unroll
    for (int j = 0; j < 4; ++j)
        d8[tid + j * 256] = s8[tid + j * 256];
}

// ---------------------------------------------------------------- 256x256 BK=64 GEMM
// (R10-verified config: best measured.) Min-sync K-loop: one barrier + one
// late vmcnt(0) per K-tile; stage tile w+1 at top of iter w. 32x32x16 MFMA.
// A and B in TILED v1 format: staging = linear 16KB copies; fragment reads =
// contiguous 1024B blocks (0 bank conflicts). 8 waves (2M x 4N), 128x64/wave.
// C/D layout (m74/m101): col=lane&31, row=(reg&3)+8*(reg>>2)+4*(lane>>5).
// EPI: 0 silu->bf16 TILED | 3 f32 nt row-major | 4 slab0 sigmoid->f16 /
//      slab1 sigmoid->bf16 / slab2 tanh->bf16 (row-major per-slab)
template<int EPI>
__global__ __launch_bounds__(512, 2)
void gemm256(const bf16_t* __restrict__ A, const bf16_t* __restrict__ Bw,
             const float* __restrict__ bi0, const float* __restrict__ bi1,
             const float* __restrict__ bi2,
             void* __restrict__ out0, void* __restrict__ out1, void* __restrict__ out2,
             int M, int N, int K)
{
    extern __shared__ char lds[];
    const int tid  = threadIdx.x;
    const int lane = tid & 63;
    const int wv   = tid >> 6;
    const int wr   = wv >> 2;      // 0..1  (M waves, 128 rows each)
    const int wc   = wv & 3;       // 0..3  (N waves, 64 cols each)
    const int l32  = lane & 31;
    const int lh   = lane >> 5;    // k-half selector

    // ---- bijective XCD-chunk swizzle (nwg % 8 == 0 for all our grids) ----
    int bid = blockIdx.y * gridDim.x + blockIdx.x;
    int nwg = gridDim.x * gridDim.y;
    int swz = (bid & 7) * (nwg >> 3) + (bid >> 3);
    int gx  = N >> 8;
    int n0  = (swz % gx) << 8;
    int m0  = (swz / gx) << 8;

    const int ktiles = K >> 6;     // col-tiles per row-tile (16)
    const size_t g0 = (size_t)tid * 8, g1 = (size_t)(512 + tid) * 8;  // linear
    const int d0 = wv << 10, d1 = 8192 + (wv << 10);   // linear LDS dest

    auto STAGE = [&](const bf16_t* G, int row0, int k0, int lds_base) {
        const bf16_t* base = G + (size_t)((row0 >> 7) * ktiles + (k0 >> 6)) * 8192;
        async16(base + g0, lds + lds_base + d0);
        async16(base + g1, lds + lds_base + d1);
    };
    auto STAGE_TILE = [&](int w, int bufo) {
        const int k0 = w << 6;
        STAGE(A,  m0,        k0, bufo);
        STAGE(A,  m0 + 128,  k0, bufo + 16384);
        STAGE(Bw, n0,        k0, bufo + 32768);
        STAGE(Bw, n0 + 128,  k0, bufo + 49152);
    };

    // ---- fragment read offsets: contiguous 1024B block per (blk, ks) ----
    const int lane16 = lane << 4;
    int offA[4][4], offB[2][4];
#pragma unroll
    for (int m = 0; m < 4; ++m)
#pragma unroll
        for (int ks = 0; ks < 4; ++ks)
            offA[m][ks] = (m << 12) + (ks << 10) + lane16;
#pragma unroll
    for (int n = 0; n < 2; ++n)
#pragma unroll
        for (int ks = 0; ks < 4; ++ks)
            offB[n][ks] = ((((wc & 1) << 1) + n) << 12) + (ks << 10) + lane16;

    f32x16 acc[4][2];
#pragma unroll
    for (int i = 0; i < 4; ++i)
#pragma unroll
        for (int j = 0; j < 2; ++j)
            acc[i][j] = (f32x16)(0.f);

    const int NT = K >> 6;   // 16

    // ---- prologue: stage tile 0 only ----
    STAGE_TILE(0, 0);
    asm volatile("s_waitcnt vmcnt(0)" ::: "memory");
    asm volatile("s_barrier" ::: "memory");

    for (int w = 0; w < NT; ++w) {
        const int bufo  = (w & 1) << 16;
        const int nbufo = bufo ^ 65536;
        const int aReg = bufo + (wr << 14);                  // A half for this wave
        const int bReg = bufo + 32768 + ((wc >> 1) << 14);   // B half for this wave

        // stage next tile into the buffer whose reads finished last iteration
        if (w + 1 < NT) STAGE_TILE(w + 1, nbufo);

#pragma unroll
        for (int ks = 0; ks < 4; ++ks) {
            bf16x8 aF[4], bF[2];
#pragma unroll
            for (int m = 0; m < 4; ++m)
                aF[m] = *reinterpret_cast<const bf16x8*>(lds + aReg + offA[m][ks]);
#pragma unroll
            for (int n = 0; n < 2; ++n)
                bF[n] = *reinterpret_cast<const bf16x8*>(lds + bReg + offB[n][ks]);
            __builtin_amdgcn_s_setprio(1);
#pragma unroll
            for (int m = 0; m < 4; ++m)
#pragma unroll
                for (int n = 0; n < 2; ++n)
                    acc[m][n] = __builtin_amdgcn_mfma_f32_32x32x16_bf16(aF[m], bF[n], acc[m][n], 0, 0, 0);
            __builtin_amdgcn_s_setprio(0);
        }

        if (w + 1 < NT) {
            // stage of tile w+1 was issued a full K-tile ago -> drain ~free
            asm volatile("s_waitcnt vmcnt(0)" ::: "memory");
            asm volatile("s_barrier" ::: "memory");
        }
    }

    // ---- epilogue: 32x32 C/D layout col=lane&31, row=(reg&3)+8*(reg>>2)+4*lh ----
    const int slab = n0 >> 10;                 // block-uniform (EPI==4)
    const float* bia = (EPI == 4) ? (slab == 0 ? bi0 : slab == 1 ? bi1 : bi2) : nullptr;
#pragma unroll
    for (int nf = 0; nf < 2; ++nf) {
        const int colg = n0 + wc * 64 + nf * 32 + l32;
        const int cL = colg & (kD - 1);
        float bs = 0.f;
        if constexpr (EPI == 4) bs = bia[cL];
#pragma unroll
        for (int mf = 0; mf < 4; ++mf) {
            const int rbase = m0 + wr * 128 + mf * 32 + lh * 4;
#pragma unroll
            for (int rg = 0; rg < 16; ++rg) {
                const int rowg = rbase + (rg & 3) + ((rg >> 2) << 3);
                const float f = acc[mf][nf][rg];
                if constexpr (EPI == 0) {
                    float s = f * fast_sigmoid(f);
                    reinterpret_cast<bf16_t*>(out0)[tiled_idx(rowg, colg, N >> 6)] = (bf16_t)s;
                } else if constexpr (EPI == 3) {
                    __builtin_nontemporal_store(f, reinterpret_cast<float*>(out0) + (size_t)rowg * N + colg);
                } else {  // EPI == 4
                    const size_t idx = (size_t)rowg * kD + cL;
                    if (slab == 0) {
                        reinterpret_cast<f16_t*>(out0)[idx] = (f16_t)fast_sigmoid(f + bs);
                    } else if (slab == 1) {
                        reinterpret_cast<bf16_t*>(out1)[idx] = (bf16_t)fast_sigmoid(f + bs);
                    } else {
                        reinterpret_cast<bf16_t*>(out2)[idx] = (bf16_t)fast_tanh(f + bs);
                    }
                }
            }
        }
    }
}

// ---------------------------------------------------------------- chunked linear scan
// 2 channels (d, d+1) per thread: 4B paired loads of alpha(f16)/beta/v(bf16).
__global__ void scan_chunk_kernel(const f16_t* __restrict__ alpha,
                                  const bf16_t* __restrict__ beta,
                                  const bf16_t* __restrict__ vv,
                                  float* __restrict__ Aagg,
                                  float* __restrict__ Bagg)
{
    const int u2  = blockIdx.x * blockDim.x + threadIdx.x;  // pair id
    const int ch2 = u2 & 2047;
    const int c   = u2 >> 11;
    const int b   = ch2 >> 9;
    const int d   = (ch2 & 511) << 1;
    size_t base = ((size_t)b * kT + (size_t)c * kL) * kD + d;
    float A0 = 1.f, B0 = 0.f, A1 = 1.f, B1 = 0.f;
#pragma unroll 4
    for (int t = 0; t < kL; ++t) {
        f16x2  a2 = *reinterpret_cast<const f16x2*>(alpha + base);
        bf16x2 b2 = *reinterpret_cast<const bf16x2*>(beta + base);
        bf16x2 v2 = *reinterpret_cast<const bf16x2*>(vv + base);
        float bv0 = (float)b2[0] * (float)v2[0];
        float bv1 = (float)b2[1] * (float)v2[1];
        A0 *= (float)a2[0]; B0 = (float)a2[0] * B0 + bv0;
        A1 *= (float)a2[1]; B1 = (float)a2[1] * B1 + bv1;
        base += kD;
    }
    const size_t o = (size_t)c * kCH + 2 * ch2;
    *reinterpret_cast<float2*>(Aagg + o) = make_float2(A0, A1);
    *reinterpret_cast<float2*>(Bagg + o) = make_float2(B0, B1);
}

__global__ void scan_mid_kernel(const float* __restrict__ Aagg,
                                const float* __restrict__ Bagg,
                                float* __restrict__ Hin,
                                float* __restrict__ hlast)
{
    const int ch = blockIdx.x * blockDim.x + threadIdx.x;
    float h = 0.f;
#pragma unroll 8
    for (int c = 0; c < kNC; ++c) {
        Hin[(size_t)c * kCH + ch] = h;
        h = Aagg[(size_t)c * kCH + ch] * h + Bagg[(size_t)c * kCH + ch];
    }
    hlast[ch] = h;
}

// writes cell in TILED v1 format; 2 channels per thread (bf16x2 stores).
__global__ void scan_out_kernel(const f16_t* __restrict__ alpha,
                                const bf16_t* __restrict__ beta,
                                const bf16_t* __restrict__ vv,
                                const float* __restrict__ Hin,
                                bf16_t* __restrict__ cell)
{
    const int u2  = blockIdx.x * blockDim.x + threadIdx.x;
    const int ch2 = u2 & 2047;
    const int c   = u2 >> 11;
    const int b   = ch2 >> 9;
    const int d   = (ch2 & 511) << 1;
    size_t base = ((size_t)b * kT + (size_t)c * kL) * kD + d;
    // tiled dest for rows r = b*kT + c*kL + t: rt = b*32 + (c>>2), mb = c&3,
    // (r&31) = t.  Pair (d, d+1) is contiguous in the (c&7) slot.
    const size_t tb = (size_t)((b * 32 + (c >> 2)) * 16 + (d >> 6)) * 8192
                    + ((size_t)(c & 3) << 11) + (((d >> 4) & 3) << 9)
                    + (((d >> 3) & 1) << 8) + (d & 7);
    float2 h2 = *reinterpret_cast<const float2*>(Hin + (size_t)c * kCH + 2 * ch2);
    float h0 = h2.x, h1 = h2.y;
#pragma unroll 4
    for (int t = 0; t < kL; ++t) {
        f16x2  a2 = *reinterpret_cast<const f16x2*>(alpha + base);
        bf16x2 b2 = *reinterpret_cast<const bf16x2*>(beta + base);
        bf16x2 v2 = *reinterpret_cast<const bf16x2*>(vv + base);
        h0 = (float)a2[0] * h0 + (float)b2[0] * (float)v2[0];
        h1 = (float)a2[1] * h1 + (float)b2[1] * (float)v2[1];
        bf16x2 o;
        o[0] = (bf16_t)(h0 * h0 * fast_sigmoid(h0));
        o[1] = (bf16_t)(h1 * h1 * fast_sigmoid(h1));
        *reinterpret_cast<bf16x2*>(cell + tb + t * 8) = o;
        base += kD;
    }
}

// ---------------------------------------------------------------- launch
extern "C" void kernel_launch(void* const* d_in, const int* in_sizes, int n_in,
                              void* d_out, int out_size, void* d_ws, size_t ws_size,
                              hipStream_t stream)
{
    const float* x     = (const float*)d_in[0];
    const float* W_in  = (const float*)d_in[1];
    const float* W_al  = (const float*)d_in[2];
    const float* b_al  = (const float*)d_in[3];
    const float* W_be  = (const float*)d_in[4];
    const float* b_be  = (const float*)d_in[5];
    const float* W_v   = (const float*)d_in[6];
    const float* b_v   = (const float*)d_in[7];
    const float* W_out = (const float*)d_in[8];

    float* out   = (float*)d_out;
    float* hlast = out + (size_t)kM * kD;

    char* ws = (char*)d_ws;
    size_t off = 0;
    auto alloc = [&](size_t bytes) -> void* {
        void* p = ws + off;
        off += (bytes + 255) & ~(size_t)255;
        return p;
    };
    bf16_t* xbf   = (bf16_t*)alloc((size_t)kM * kD * 2);   // tiled; reused as cell
    bf16_t* xp    = (bf16_t*)alloc((size_t)kM * kD * 2);   // tiled; reused for aggs
    f16_t*  alpha = (f16_t*) alloc((size_t)kM * kD * 2);
    bf16_t* betab = (bf16_t*)alloc((size_t)kM * kD * 2);
    bf16_t* vb    = (bf16_t*)alloc((size_t)kM * kD * 2);
    bf16_t* wbf   = (bf16_t*)alloc((size_t)5 * kD * kD * 2);

    bf16_t* Winb = wbf;                         // tiled [W_in; W_al; W_be; W_v; W_out]
    bf16_t* Wfus = wbf + 1 * (size_t)kD * kD;   // fused B: row-tiles of the 3 gates
    bf16_t* Wob  = wbf + 4 * (size_t)kD * kD;

    bf16_t* cell = xbf;
    float*  Aagg = (float*)xp;
    float*  Bagg = Aagg + (size_t)kNC * kCH;
    float*  Hin  = Bagg + (size_t)kNC * kCH;

    hipFuncSetAttribute(reinterpret_cast<const void*>(gemm256<0>), hipFuncAttributeMaxDynamicSharedMemorySize, LDS_BYTES);
    hipFuncSetAttribute(reinterpret_cast<const void*>(gemm256<3>), hipFuncAttributeMaxDynamicSharedMemorySize, LDS_BYTES);
    hipFuncSetAttribute(reinterpret_cast<const void*>(gemm256<4>), hipFuncAttributeMaxDynamicSharedMemorySize, LDS_BYTES);

    // 1) single merged tiled cast: x (2048 tiles) + 5 weights (5*128 tiles)
    cvt_all_kernel<<<2048 + 5 * 128, 256, 0, stream>>>(x, W_in, W_al, W_be, W_v, W_out,
                                                       xbf, wbf);

    dim3 grid1(kD / 256, kM / 256);     // (4, 64)  = 256 wgs
    dim3 gridF(3 * kD / 256, kM / 256); // (12, 64) = 768 wgs

    // 2) xp = silu(x @ W_in^T)                       [bf16 tiled]
    gemm256<0><<<grid1, 512, LDS_BYTES, stream>>>(xbf, Winb, nullptr, nullptr, nullptr,
                                                  xp, nullptr, nullptr, kM, kD, kD);
    // 3) fused: alpha=sigmoid(+b_al) f16 | beta=sigmoid(+b_be) bf16 | v=tanh(+b_v) bf16
    gemm256<4><<<gridF, 512, LDS_BYTES, stream>>>(xp, Wfus, b_al, b_be, b_v,
                                                  alpha, betab, vb, kM, 3 * kD, kD);
    // 4) chunked scan (2 channels/thread); cell written tiled
    scan_chunk_kernel<<<kNC * kCH / 512, 256, 0, stream>>>(alpha, betab, vb, Aagg, Bagg);
    scan_mid_kernel<<<kCH / 256, 256, 0, stream>>>(Aagg, Bagg, Hin, hlast);
    scan_out_kernel<<<kNC * kCH / 512, 256, 0, stream>>>(alpha, betab, vb, Hin, cell);

    // 5) output = cell @ W_out^T                     [f32 nt -> d_out]
    gemm256<3><<<grid1, 512, LDS_BYTES, stream>>>(cell, Wob, nullptr, nullptr, nullptr,
                                                  out, nullptr, nullptr, kM, kD, kD);
}